// Round 11
// baseline (4699.865 us; speedup 1.0000x reference)
//
#include <hip/hip_runtime.h>

// Problem constants (fixed by the reference): T=512, B=64, I=256, H=512.
#define T_DIM 512
#define B_DIM 64
#define I_DIM 256
#define H_DIM 512
#define BH_DIM (B_DIM * H_DIM)   // 32768

// ---------------------------------------------------------------------------
// Round-17: ONE kernel, heterogeneous blocks: 1024 gemm blocks (first in
// dispatch order) + 256 scan blocks (last). The scan is latency-bound
// (VALUBusy 45%, detect ~2500cy floor proven by 5 sampling variants); the
// gemm runs in its idle issue slots instead of serializing 150us ahead of
// it in the stream.
//
// Deadlock-impossibility: gemm blocks never wait on anything; scan blocks
// wait only on gemm flags. Gemm-first dispatch order means gemm drains even
// at 1 block/CU (4 rounds), after which all 256 scan blocks fit (<= 2
// slots/CU in the 16-wave bucket; exactly 256 slots in the 8-wave bucket).
// __launch_bounds__(512,4) caps VGPR at 128 -> 16 waves/CU -> gemm+scan
// co-residency for true overlap.
//
// In-kernel xw handoff (no kernel-boundary cache flush exists anymore!):
//  - gemm writes xw with AGENT-scope relaxed stores (MALL-coherent path,
//    same as the proven stage protocol; regular stores would sit dirty in
//    the writer XCD's L2, invisible cross-XCD).
//  - per-tile flags[bm*4+bn] released after a store-draining __syncthreads
//    (barrier emits vmcnt(0) -> all stores acked), acquired by scan.
//  - scan reads xw with AGENT-scope relaxed loads, gated by the flag
//    (one acquire check per 2 steps, off the critical path).
//  - flags zeroed per launch via hipMemsetAsync (graph-legal) -> no stale
//    flag across graph replays.
// FMA orders identical to R11/R14 -> bit-identical output.
//
// Scan path = R14 byte-identical (best, 734us): 4 row-chunks x 64 batches,
// W_hh in regs (w[4][8]), DPP 16-lane reduce, agent tagged words (tag t+1),
// parity double-buffer, one barrier/step, spec-poll-before-stores,
// post-barrier xw prefetch.
// ---------------------------------------------------------------------------

// 16-lane sum on the VALU pipe (DPP): quad_perm 0xB1, 0x4E, row_ror:4, :8.
__device__ __forceinline__ float row16_sum(float v) {
  int m;
  m = __builtin_amdgcn_update_dpp(0, __float_as_int(v), 0xB1, 0xF, 0xF, true);
  v += __int_as_float(m);
  m = __builtin_amdgcn_update_dpp(0, __float_as_int(v), 0x4E, 0xF, 0xF, true);
  v += __int_as_float(m);
  m = __builtin_amdgcn_update_dpp(0, __float_as_int(v), 0x124, 0xF, 0xF, true);
  v += __int_as_float(m);
  m = __builtin_amdgcn_update_dpp(0, __float_as_int(v), 0x128, 0xF, 0xF, true);
  v += __int_as_float(m);
  return v;
}

// hh accumulation: 4 rows x 8 float4 + 16-lane reduce; result valid cg<4.
__device__ __forceinline__ float hh_acc(const float* hb,
                                        const float4 (&w)[4][8], int cg) {
  float a0 = 0.f, a1 = 0.f, a2 = 0.f, a3 = 0.f;
#pragma unroll
  for (int i = 0; i < 8; i++) {
    const float4 hv = ((const float4*)hb)[i * 16 + cg];
    a0 = fmaf(w[0][i].x, hv.x, a0); a0 = fmaf(w[0][i].y, hv.y, a0);
    a0 = fmaf(w[0][i].z, hv.z, a0); a0 = fmaf(w[0][i].w, hv.w, a0);
    a1 = fmaf(w[1][i].x, hv.x, a1); a1 = fmaf(w[1][i].y, hv.y, a1);
    a1 = fmaf(w[1][i].z, hv.z, a1); a1 = fmaf(w[1][i].w, hv.w, a1);
    a2 = fmaf(w[2][i].x, hv.x, a2); a2 = fmaf(w[2][i].y, hv.y, a2);
    a2 = fmaf(w[2][i].z, hv.z, a2); a2 = fmaf(w[2][i].w, hv.w, a2);
    a3 = fmaf(w[3][i].x, hv.x, a3); a3 = fmaf(w[3][i].y, hv.y, a3);
    a3 = fmaf(w[3][i].z, hv.z, a3); a3 = fmaf(w[3][i].w, hv.w, a3);
  }
  a0 = row16_sum(a0);
  a1 = row16_sum(a1);
  a2 = row16_sum(a2);
  a3 = row16_sum(a3);
  return (cg == 0) ? a0 : (cg == 1) ? a1 : (cg == 2) ? a2 : a3;
}

__global__ __launch_bounds__(512, 4) void rnn_mega(
    const float* __restrict__ x, const float* __restrict__ wih,
    const float* __restrict__ whh, const float* __restrict__ bih,
    const float* __restrict__ bhh, float* __restrict__ out,
    unsigned long long* __restrict__ stage,
    unsigned int* __restrict__ flags) {
  __shared__ __align__(16) float hbuf[2][H_DIM];  // scan: 4 KB
  __shared__ __align__(16) float As[32][128];     // gemm: 16 KB [k][m]
  __shared__ __align__(16) float Bs[32][128];     // gemm: 16 KB [k][n]

  const int tid = threadIdx.x;  // 0..511

  if (blockIdx.x < 1024) {
    // ================== GEMM path: xw tile (bm, bn) ==================
    const int gid = blockIdx.x;
    const int bm = gid >> 2, bn = gid & 3;
    const int m0 = bm * 128, n0 = bn * 128;
    const int tx = tid & 15, ty = tid >> 4;  // micro-tile 4m x 8n

    float acc[4][8];
#pragma unroll
    for (int r = 0; r < 4; r++)
#pragma unroll
      for (int c = 0; c < 8; c++) acc[r][c] = 0.f;

    for (int kc = 0; kc < I_DIM; kc += 32) {
      float4 av[2], bv[2];
#pragma unroll
      for (int q = 0; q < 2; q++) {
        const int idx = q * 512 + tid;      // 0..1023
        const int ml = idx & 127, kq = idx >> 7;
        av[q] = *(const float4*)(x + (size_t)(m0 + ml) * I_DIM + kc + kq * 4);
        bv[q] = *(const float4*)(wih + (size_t)(n0 + ml) * I_DIM + kc + kq * 4);
      }
      __syncthreads();  // previous chunk consumed
#pragma unroll
      for (int q = 0; q < 2; q++) {
        const int idx = q * 512 + tid;
        const int ml = idx & 127, kq = idx >> 7;
        As[kq * 4 + 0][ml] = av[q].x; As[kq * 4 + 1][ml] = av[q].y;
        As[kq * 4 + 2][ml] = av[q].z; As[kq * 4 + 3][ml] = av[q].w;
        Bs[kq * 4 + 0][ml] = bv[q].x; Bs[kq * 4 + 1][ml] = bv[q].y;
        Bs[kq * 4 + 2][ml] = bv[q].z; Bs[kq * 4 + 3][ml] = bv[q].w;
      }
      __syncthreads();

#pragma unroll 8
      for (int kk = 0; kk < 32; kk++) {
        const float4 a = *(const float4*)&As[kk][ty * 4];
        const float4 b0 = *(const float4*)&Bs[kk][tx * 8];
        const float4 b1 = *(const float4*)&Bs[kk][tx * 8 + 4];
        const float ar[4] = {a.x, a.y, a.z, a.w};
        const float br_[8] = {b0.x, b0.y, b0.z, b0.w, b1.x, b1.y, b1.z, b1.w};
#pragma unroll
        for (int r = 0; r < 4; r++)
#pragma unroll
          for (int c = 0; c < 8; c++)
            acc[r][c] = fmaf(ar[r], br_[c], acc[r][c]);
      }
    }

    // bias + agent-scope stores (MALL-coherent: visible to scan's agent
    // loads without a kernel boundary; regular stores would sit dirty in
    // this XCD's L2 and be invisible cross-XCD).
    float bb[8];
#pragma unroll
    for (int c = 0; c < 8; c++)
      bb[c] = bih[n0 + tx * 8 + c] + bhh[n0 + tx * 8 + c];
#pragma unroll
    for (int r = 0; r < 4; r++) {
      const int m = m0 + ty * 4 + r;
      unsigned int* orow =
          (unsigned int*)(out + (size_t)m * H_DIM + n0 + tx * 8);
#pragma unroll
      for (int c = 0; c < 8; c++) {
        union { float f; unsigned int u; } cv; cv.f = acc[r][c] + bb[c];
        __hip_atomic_store(&orow[c], cv.u, __ATOMIC_RELAXED,
                           __HIP_MEMORY_SCOPE_AGENT);
      }
    }
    __syncthreads();  // barrier drains vmcnt(0): all tile stores acked
    if (tid == 0)
      __hip_atomic_store(&flags[bm * 4 + bn], 1u, __ATOMIC_RELEASE,
                         __HIP_MEMORY_SCOPE_AGENT);
    return;
  }

  // ================== scan path (R14 + flag-gated agent xw) ==================
  const int sid = blockIdx.x - 1024;
  const int b   = sid & 63;
  const int rb  = sid >> 6;              // row-chunk 0..3
  const int rg  = tid >> 4;              // 0..31
  const int cg  = tid & 15;              // 0..15
  const int j0  = rb * 128 + rg * 4;     // first of my 4 rows
  const int jj  = j0 + cg;               // publish index (cg<4 lanes)

  const int pj = (tid < rb * 128) ? tid : tid + 128;
  const bool poller = (tid < 384);

  // ---- W_hh chunk -> registers (once) ----
  float4 w[4][8];
#pragma unroll
  for (int r = 0; r < 4; r++) {
    const float4* wr = (const float4*)(whh + (size_t)(j0 + r) * H_DIM);
#pragma unroll
    for (int i = 0; i < 8; i++) w[r][i] = wr[i * 16 + cg];
  }

  float* __restrict__ outb = out + (size_t)b * H_DIM;  // t-stride = BH_DIM
  unsigned long long* __restrict__ stg0 = stage + (size_t)b * H_DIM;
  unsigned long long* __restrict__ stg1 = stage + (size_t)(64 + b) * H_DIM;

  float hlast = 0.f;

  // ---- gate xw[0..1] (gemm tile bm=0, bn=rb) ----
  while (__hip_atomic_load(&flags[rb], __ATOMIC_ACQUIRE,
                           __HIP_MEMORY_SCOPE_AGENT) == 0)
    __builtin_amdgcn_s_sleep(2);
  int done_bm = 0;

  // ---- t = 0: h_0 = relu(xw_0); publish (tag 1, parity 0) ----
  if (cg < 4) {
    union { unsigned int u; float f; } c0;
    c0.u = __hip_atomic_load((const unsigned int*)&outb[jj], __ATOMIC_RELAXED,
                             __HIP_MEMORY_SCOPE_AGENT);
    const float h = fmaxf(c0.f, 0.f);
    union { float f; unsigned int u; } cv; cv.f = h;
    __hip_atomic_store(&stg0[jj], (1ULL << 32) | (unsigned long long)cv.u,
                       __ATOMIC_RELAXED, __HIP_MEMORY_SCOPE_AGENT);
    __builtin_nontemporal_store(h, &outb[jj]);
    hbuf[0][jj] = h;
    hlast = h;
  }

  // prologue: spec poll load for t=1 (parity 0), then xw for t=1
  unsigned long long* slot = stg0 + pj;
  unsigned long long v = 0;
  if (poller)
    v = __hip_atomic_load(slot, __ATOMIC_RELAXED, __HIP_MEMORY_SCOPE_AGENT);
  float xwv = 0.f;
  if (cg < 4) {
    union { unsigned int u; float f; } cx;
    cx.u = __hip_atomic_load((const unsigned int*)&outb[(size_t)BH_DIM + jj],
                             __ATOMIC_RELAXED, __HIP_MEMORY_SCOPE_AGENT);
    xwv = cx.f;
  }

  // ---- main scan ----
  for (int t = 1; t < T_DIM; t++) {
    const int p = (t - 1) & 1;  // parity of h_{t-1}
    const unsigned int want = (unsigned int)t;  // tag carried by h_{t-1}
    float* o_t = outb + (size_t)t * BH_DIM;

    // A. finish the poll (spec load from loop bottom; counted vmcnt skips
    //    the newer store acks).
    if (poller) {
      while ((unsigned int)(v >> 32) != want)
        v = __hip_atomic_load(slot, __ATOMIC_RELAXED,
                              __HIP_MEMORY_SCOPE_AGENT);
      union { unsigned int u; float f; } cv; cv.u = (unsigned int)v;
      hbuf[p][pj] = cv.f;
    }

    __syncthreads();  // h_{t-1} complete in LDS

    // B. xw prefetch for t+1, gated by the gemm tile flag (one acquire
    //    check per 2 steps; off the critical path -- consumed next publish)
    float xw_n = 0.f;
    if (t + 1 < T_DIM) {
      const int bmn = (t + 1) >> 1;
      if (bmn > done_bm) {
        while (__hip_atomic_load(&flags[bmn * 4 + rb], __ATOMIC_ACQUIRE,
                                 __HIP_MEMORY_SCOPE_AGENT) == 0)
          __builtin_amdgcn_s_sleep(2);
        done_bm = bmn;
      }
      if (cg < 4) {
        union { unsigned int u; float f; } cx;
        cx.u = __hip_atomic_load(
            (const unsigned int*)&outb[(size_t)(t + 1) * BH_DIM + jj],
            __ATOMIC_RELAXED, __HIP_MEMORY_SCOPE_AGENT);
        xw_n = cx.f;
      }
    }

    // C. hh-fma + DPP reduce
    const float acc = hh_acc(hbuf[p], w, cg);

    // D. spec poll load for t+1, BEFORE the publish/out stores (counted
    //    vmcnt at next loop top skips store acks).
    if (poller) {
      slot = ((t & 1) ? stg1 : stg0) + pj;
      v = __hip_atomic_load(slot, __ATOMIC_RELAXED, __HIP_MEMORY_SCOPE_AGENT);
    }
    __builtin_amdgcn_sched_barrier(0);

    // E. publish h_t (tag t+1; 16 contiguous tagged words per wave)
    if (cg < 4) {
      const float h = fmaxf(acc + xwv, 0.f);
      union { float f; unsigned int u; } cv; cv.f = h;
      unsigned long long* sb = (t & 1) ? stg1 : stg0;
      __hip_atomic_store(&sb[jj],
                         ((unsigned long long)(unsigned int)(t + 1) << 32) |
                             (unsigned long long)cv.u,
                         __ATOMIC_RELAXED, __HIP_MEMORY_SCOPE_AGENT);
      __builtin_nontemporal_store(h, &o_t[jj]);  // output[t,b,j]
      hbuf[t & 1][jj] = h;    // own rows for next step
      hlast = h;
    }

    xwv = xw_n;
  }

  // h_final = h_{T-1}
  if (cg < 4) {
    __builtin_nontemporal_store(
        hlast, &out[(size_t)T_DIM * BH_DIM + (size_t)b * H_DIM + jj]);
  }
}

extern "C" void kernel_launch(void* const* d_in, const int* in_sizes, int n_in,
                              void* d_out, int out_size, void* d_ws, size_t ws_size,
                              hipStream_t stream) {
  const float* x   = (const float*)d_in[0];  // [T,B,I]
  const float* wih = (const float*)d_in[1];  // [H,I]
  const float* whh = (const float*)d_in[2];  // [H,H]
  const float* bih = (const float*)d_in[3];  // [H]
  const float* bhh = (const float*)d_in[4];  // [H]
  float* out = (float*)d_out;                // [T,B,H] output ++ [B,H] h_final
  // workspace: stage (512 KB) ++ flags (1024 x u32 = 4 KB)
  unsigned long long* stage = (unsigned long long*)d_ws;
  unsigned int* flags = (unsigned int*)(stage + 2 * 64 * 512);

  // zero the gemm-tile flags each launch (graph-capture-legal async memset;
  // stale flags from a prior replay would break the xw handoff ordering)
  hipMemsetAsync(flags, 0, 1024 * sizeof(unsigned int), stream);

  // one kernel: 1024 gemm blocks (dispatch first; never wait) + 256 scan
  // blocks (dispatch last; wait only on gemm flags) -> deadlock-free in
  // every occupancy bucket, overlapped when 16 waves/CU fit.
  rnn_mega<<<1280, 512, 0, stream>>>(x, wih, whh, bih, bhh, out, stage, flags);
}

// Round 12
// 882.153 us; speedup vs baseline: 5.3277x; 5.3277x over previous
//
#include <hip/hip_runtime.h>

// Problem constants (fixed by the reference): T=512, B=64, I=256, H=512.
#define T_DIM 512
#define B_DIM 64
#define I_DIM 256
#define H_DIM 512
#define BH_DIM (B_DIM * H_DIM)   // 32768

// ---------------------------------------------------------------------------
// Round-18: R14 (best total 885us: scan 734 + gemm ~148) with ONE change:
// the gemm register-double-buffers its staging loads (m97 pattern).
//
// R17 post-mortem: mega-kernel died of VGPR spill (launch_bounds(512,4) ->
// 64 VGPR cap -> w[4][8] spilled -> 886MB scratch traffic, VALU 7%).
// Overlap prize (~70-80us) not worth the fabric-pressure risk vs this fix.
//
// R11 gemm flaw: per K-chunk, global loads are issued right BEFORE
// __syncthreads, whose implicit vmcnt(0) drains them -> a full ~700cy RT
// exposed at every chunk x 8. Fix: issue chunk k+1 loads BEFORE computing
// chunk k (compute ~4096cy >> RT retires them); barrier then drains
// already-complete loads. FMA order unchanged -> bit-identical output.
//
// Scan = R14 rnn_scan4 BYTE-IDENTICAL (proven 734us floor: 5 sampling
// variants all plateau at detect ~2500cy = cross-XCD visibility).
// ---------------------------------------------------------------------------

// ---------------- Kernel 1: xw pre-pass GEMM (reg-dbuf prefetch) ----------------
__global__ __launch_bounds__(256) void xw_gemm(
    const float* __restrict__ x, const float* __restrict__ wih,
    const float* __restrict__ bih, const float* __restrict__ bhh,
    float* __restrict__ out) {
  __shared__ __align__(16) float As[32][128];  // [k][m]
  __shared__ __align__(16) float Bs[32][128];  // [k][n]

  const int bm = blockIdx.x >> 2;   // 0..255 (m-tile)
  const int bn = blockIdx.x & 3;    // 0..3   (n-tile; fastest -> A-tile L2 reuse)
  const int m0 = bm * 128, n0 = bn * 128;
  const int tid = threadIdx.x;      // 0..255
  const int tx = tid & 15, ty = tid >> 4;
  const int ml = tid & 127, kq = tid >> 7;  // staging map

  const float* xrow = x + (size_t)(m0 + ml) * I_DIM + kq * 16;
  const float* brow = wih + (size_t)(n0 + ml) * I_DIM + kq * 16;

  float acc[8][8];
#pragma unroll
  for (int r = 0; r < 8; r++)
#pragma unroll
    for (int c = 0; c < 8; c++) acc[r][c] = 0.f;

  // prologue: load + stage chunk 0 (no prior LDS readers -> single barrier)
  float4 av[4], bv[4];
#pragma unroll
  for (int j = 0; j < 4; j++) {
    av[j] = *(const float4*)(xrow + 0 + j * 4);
    bv[j] = *(const float4*)(brow + 0 + j * 4);
  }
#pragma unroll
  for (int j = 0; j < 4; j++) {
    const int k = kq * 16 + j * 4;
    As[k + 0][ml] = av[j].x; As[k + 1][ml] = av[j].y;
    As[k + 2][ml] = av[j].z; As[k + 3][ml] = av[j].w;
    Bs[k + 0][ml] = bv[j].x; Bs[k + 1][ml] = bv[j].y;
    Bs[k + 2][ml] = bv[j].z; Bs[k + 3][ml] = bv[j].w;
  }
  __syncthreads();

  for (int ch = 0; ch < 8; ch++) {
    // issue chunk ch+1 loads EARLY: they retire under the ~4096cy compute,
    // so the next barrier's implicit vmcnt(0) drain costs nothing.
    if (ch + 1 < 8) {
      const int kc = (ch + 1) * 32;
#pragma unroll
      for (int j = 0; j < 4; j++) {
        av[j] = *(const float4*)(xrow + kc + j * 4);
        bv[j] = *(const float4*)(brow + kc + j * 4);
      }
    }

    // compute chunk ch from LDS (FMA order identical to R11)
#pragma unroll 4
    for (int kk = 0; kk < 32; kk++) {
      const float4 a0 = *(const float4*)&As[kk][ty * 4];
      const float4 a1 = *(const float4*)&As[kk][64 + ty * 4];
      const float4 b0 = *(const float4*)&Bs[kk][tx * 4];
      const float4 b1 = *(const float4*)&Bs[kk][64 + tx * 4];
      const float ar[8] = {a0.x, a0.y, a0.z, a0.w, a1.x, a1.y, a1.z, a1.w};
      const float br_[8] = {b0.x, b0.y, b0.z, b0.w, b1.x, b1.y, b1.z, b1.w};
#pragma unroll
      for (int r = 0; r < 8; r++)
#pragma unroll
        for (int c = 0; c < 8; c++) acc[r][c] = fmaf(ar[r], br_[c], acc[r][c]);
    }

    if (ch + 1 < 8) {
      __syncthreads();  // LDS consumed; staged loads already retired
#pragma unroll
      for (int j = 0; j < 4; j++) {
        const int k = kq * 16 + j * 4;
        As[k + 0][ml] = av[j].x; As[k + 1][ml] = av[j].y;
        As[k + 2][ml] = av[j].z; As[k + 3][ml] = av[j].w;
        Bs[k + 0][ml] = bv[j].x; Bs[k + 1][ml] = bv[j].y;
        Bs[k + 2][ml] = bv[j].z; Bs[k + 3][ml] = bv[j].w;
      }
      __syncthreads();
    }
  }

  // bias add + store (unchanged)
  const float4 bi0 = *(const float4*)(bih + n0 + tx * 4);
  const float4 bh0 = *(const float4*)(bhh + n0 + tx * 4);
  const float4 bi1 = *(const float4*)(bih + n0 + 64 + tx * 4);
  const float4 bh1 = *(const float4*)(bhh + n0 + 64 + tx * 4);
  const float4 bb0 = make_float4(bi0.x + bh0.x, bi0.y + bh0.y, bi0.z + bh0.z, bi0.w + bh0.w);
  const float4 bb1 = make_float4(bi1.x + bh1.x, bi1.y + bh1.y, bi1.z + bh1.z, bi1.w + bh1.w);

#pragma unroll
  for (int r = 0; r < 8; r++) {
    const int m = m0 + ((r < 4) ? (ty * 4 + r) : (64 + ty * 4 + (r - 4)));
    float4* orow = (float4*)(out + (size_t)m * H_DIM + n0);
    orow[tx] = make_float4(acc[r][0] + bb0.x, acc[r][1] + bb0.y,
                           acc[r][2] + bb0.z, acc[r][3] + bb0.w);
    orow[16 + tx] = make_float4(acc[r][4] + bb1.x, acc[r][5] + bb1.y,
                                acc[r][6] + bb1.z, acc[r][7] + bb1.w);
  }
}

// ---------------- Kernel 2: recurrent scan (R14 byte-identical) ----------------

// 16-lane sum on the VALU pipe (DPP): quad_perm 0xB1, 0x4E, row_ror:4, :8.
__device__ __forceinline__ float row16_sum(float v) {
  int m;
  m = __builtin_amdgcn_update_dpp(0, __float_as_int(v), 0xB1, 0xF, 0xF, true);
  v += __int_as_float(m);
  m = __builtin_amdgcn_update_dpp(0, __float_as_int(v), 0x4E, 0xF, 0xF, true);
  v += __int_as_float(m);
  m = __builtin_amdgcn_update_dpp(0, __float_as_int(v), 0x124, 0xF, 0xF, true);
  v += __int_as_float(m);
  m = __builtin_amdgcn_update_dpp(0, __float_as_int(v), 0x128, 0xF, 0xF, true);
  v += __int_as_float(m);
  return v;
}

// hh accumulation: 4 rows x 8 float4 + 16-lane reduce; result valid cg<4.
__device__ __forceinline__ float hh_acc(const float* hb,
                                        const float4 (&w)[4][8], int cg) {
  float a0 = 0.f, a1 = 0.f, a2 = 0.f, a3 = 0.f;
#pragma unroll
  for (int i = 0; i < 8; i++) {
    const float4 hv = ((const float4*)hb)[i * 16 + cg];
    a0 = fmaf(w[0][i].x, hv.x, a0); a0 = fmaf(w[0][i].y, hv.y, a0);
    a0 = fmaf(w[0][i].z, hv.z, a0); a0 = fmaf(w[0][i].w, hv.w, a0);
    a1 = fmaf(w[1][i].x, hv.x, a1); a1 = fmaf(w[1][i].y, hv.y, a1);
    a1 = fmaf(w[1][i].z, hv.z, a1); a1 = fmaf(w[1][i].w, hv.w, a1);
    a2 = fmaf(w[2][i].x, hv.x, a2); a2 = fmaf(w[2][i].y, hv.y, a2);
    a2 = fmaf(w[2][i].z, hv.z, a2); a2 = fmaf(w[2][i].w, hv.w, a2);
    a3 = fmaf(w[3][i].x, hv.x, a3); a3 = fmaf(w[3][i].y, hv.y, a3);
    a3 = fmaf(w[3][i].z, hv.z, a3); a3 = fmaf(w[3][i].w, hv.w, a3);
  }
  a0 = row16_sum(a0);
  a1 = row16_sum(a1);
  a2 = row16_sum(a2);
  a3 = row16_sum(a3);
  return (cg == 0) ? a0 : (cg == 1) ? a1 : (cg == 2) ? a2 : a3;
}

__global__ __launch_bounds__(512, 2) void rnn_scan4(
    const float* __restrict__ whh, float* __restrict__ out,
    unsigned long long* __restrict__ stage) {
  __shared__ __align__(16) float hbuf[2][H_DIM];  // 4 KB h double buffer

  const int b   = blockIdx.x & 63;
  const int rb  = blockIdx.x >> 6;       // row-chunk 0..3
  const int tid = threadIdx.x;           // 0..511
  const int rg  = tid >> 4;              // 0..31
  const int cg  = tid & 15;              // 0..15
  const int j0  = rb * 128 + rg * 4;     // first of my 4 rows
  const int jj  = j0 + cg;               // publish index (cg<4 lanes)

  // spin target: one partner element each for threads 0..383 (skip own chunk)
  const int pj = (tid < rb * 128) ? tid : tid + 128;
  const bool poller = (tid < 384);

  // ---- W_hh chunk -> registers (once) ----
  float4 w[4][8];
#pragma unroll
  for (int r = 0; r < 4; r++) {
    const float4* wr = (const float4*)(whh + (size_t)(j0 + r) * H_DIM);
#pragma unroll
    for (int i = 0; i < 8; i++) w[r][i] = wr[i * 16 + cg];
  }

  float* __restrict__ outb = out + (size_t)b * H_DIM;  // t-stride = BH_DIM
  unsigned long long* __restrict__ stg0 = stage + (size_t)b * H_DIM;
  unsigned long long* __restrict__ stg1 = stage + (size_t)(64 + b) * H_DIM;

  float hlast = 0.f;

  // ---- t = 0: h_0 = relu(xw_0); publish (tag 1, parity 0) ----
  if (cg < 4) {
    const float h = fmaxf(outb[jj], 0.f);
    union { float f; unsigned int u; } cv; cv.f = h;
    __hip_atomic_store(&stg0[jj], (1ULL << 32) | (unsigned long long)cv.u,
                       __ATOMIC_RELAXED, __HIP_MEMORY_SCOPE_AGENT);
    __builtin_nontemporal_store(h, &outb[jj]);
    hbuf[0][jj] = h;
    hlast = h;
  }

  // prologue: spec poll load for t=1 (parity 0), then xw for t=1 (newer ->
  // the t=1 check's counted vmcnt does not wait for it)
  unsigned long long* slot = stg0 + pj;
  unsigned long long v = 0;
  if (poller)
    v = __hip_atomic_load(slot, __ATOMIC_RELAXED, __HIP_MEMORY_SCOPE_AGENT);
  float xwv = 0.f;
  if (cg < 4)
    xwv = __builtin_nontemporal_load(&outb[(size_t)BH_DIM + jj]);

  // ---- main scan ----
  for (int t = 1; t < T_DIM; t++) {
    const int p = (t - 1) & 1;  // parity of h_{t-1}
    const unsigned int want = (unsigned int)t;  // tag carried by h_{t-1}
    float* o_t = outb + (size_t)t * BH_DIM;

    // A. finish the poll. First check consumes the spec load issued BEFORE
    //    last iteration's stores -> counted vmcnt skips the store acks.
    if (poller) {
      while ((unsigned int)(v >> 32) != want)
        v = __hip_atomic_load(slot, __ATOMIC_RELAXED,
                              __HIP_MEMORY_SCOPE_AGENT);
      union { unsigned int u; float f; } cv; cv.u = (unsigned int)v;
      hbuf[p][pj] = cv.f;
    }

    __syncthreads();  // h_{t-1} complete in LDS

    // B. xw prefetch for t+1 (post-barrier: drains at the NEXT barrier,
    //    ~P cycles later, long retired; consumed at next publish)
    float xw_n = 0.f;
    if (cg < 4 && t + 1 < T_DIM)
      xw_n = __builtin_nontemporal_load(&outb[(size_t)(t + 1) * BH_DIM + jj]);

    // C. hh-fma + DPP reduce
    const float acc = hh_acc(hbuf[p], w, cg);

    // D. speculative poll load for t+1, issued BEFORE the publish/out
    //    stores so next iteration's check needs only vmcnt(2) (stores are
    //    newer). sched_barrier pins the order against the scheduler.
    if (poller) {
      slot = ((t & 1) ? stg1 : stg0) + pj;
      v = __hip_atomic_load(slot, __ATOMIC_RELAXED, __HIP_MEMORY_SCOPE_AGENT);
    }
    __builtin_amdgcn_sched_barrier(0);

    // E. publish h_t (tag t+1; 16 contiguous tagged words per wave)
    if (cg < 4) {
      const float h = fmaxf(acc + xwv, 0.f);
      union { float f; unsigned int u; } cv; cv.f = h;
      unsigned long long* sb = (t & 1) ? stg1 : stg0;
      __hip_atomic_store(&sb[jj],
                         ((unsigned long long)(unsigned int)(t + 1) << 32) |
                             (unsigned long long)cv.u,
                         __ATOMIC_RELAXED, __HIP_MEMORY_SCOPE_AGENT);
      __builtin_nontemporal_store(h, &o_t[jj]);  // output[t,b,j]
      hbuf[t & 1][jj] = h;    // own rows for next step
      hlast = h;
    }

    xwv = xw_n;
  }

  // h_final = h_{T-1}
  if (cg < 4) {
    __builtin_nontemporal_store(
        hlast, &out[(size_t)T_DIM * BH_DIM + (size_t)b * H_DIM + jj]);
  }
}

extern "C" void kernel_launch(void* const* d_in, const int* in_sizes, int n_in,
                              void* d_out, int out_size, void* d_ws, size_t ws_size,
                              hipStream_t stream) {
  const float* x   = (const float*)d_in[0];  // [T,B,I]
  const float* wih = (const float*)d_in[1];  // [H,I]
  const float* whh = (const float*)d_in[2];  // [H,H]
  const float* bih = (const float*)d_in[3];  // [H]
  const float* bhh = (const float*)d_in[4];  // [H]
  float* out = (float*)d_out;                // [T,B,H] output ++ [B,H] h_final
  // staging: 2 parities x 64 batches x 512 tagged 8B words = 512 KB
  unsigned long long* stage = (unsigned long long*)d_ws;

  // Pass 1: xw = x @ wih^T + bih + bhh  -> written into out[0 .. T*B*H)
  xw_gemm<<<1024, 256, 0, stream>>>(x, wih, bih, bhh, out);
  // Pass 2: scan (R14, proven 734us floor)
  rnn_scan4<<<256, 512, 0, stream>>>(whh, out, stage);
}